// Round 1
// 440.968 us; speedup vs baseline: 1.0061x; 1.0061x over previous
//
#include <hip/hip_runtime.h>
#include <cstddef>

#define BATCH   4096
#define PAD_IDX 1000000
#define NEG_INF_F (-1e9f)

typedef __attribute__((ext_vector_type(8))) short bf16x8;   // 8 bf16 = 4 VGPRs
typedef __attribute__((ext_vector_type(4))) float f32x4;
typedef unsigned short u16;

__device__ __forceinline__ u16 f2bf(float f) {              // RNE fp32 -> bf16
    unsigned u = __float_as_uint(f);
    return (u16)((u + 0x7fffu + ((u >> 16) & 1u)) >> 16);
}
__device__ __forceinline__ float bf2f(u16 b) {
    return __uint_as_float(((unsigned)b) << 16);
}

// Online-softmax update on named state (mm, dd, aa)
#define UPD(mm, dd, aa, s, v)                          \
    {                                                  \
        float nm = fmaxf(mm, (s));                     \
        float sc = __expf(mm - nm);                    \
        float e  = __expf((s) - nm);                   \
        dd = fmaf(dd, sc, e);                          \
        aa.x = fmaf(aa.x, sc, e * (v).x);              \
        aa.y = fmaf(aa.y, sc, e * (v).y);              \
        aa.z = fmaf(aa.z, sc, e * (v).z);              \
        aa.w = fmaf(aa.w, sc, e * (v).w);              \
        mm = nm;                                       \
    }

// Flash-merge state A with partner at lane^P (acts on m,d,acc)
#define MERGE(P)                                                  \
    {                                                             \
        float mo  = __shfl_xor(m, P);                             \
        float d_o = __shfl_xor(d, P);                             \
        float ax = __shfl_xor(acc.x, P);                          \
        float ay = __shfl_xor(acc.y, P);                          \
        float az = __shfl_xor(acc.z, P);                          \
        float aw = __shfl_xor(acc.w, P);                          \
        float nm = fmaxf(m, mo);                                  \
        float sA = __expf(m - nm), sB = __expf(mo - nm);          \
        d = d * sA + d_o * sB;                                    \
        acc.x = acc.x * sA + ax * sB;                             \
        acc.y = acc.y * sA + ay * sB;                             \
        acc.z = acc.z * sA + az * sB;                             \
        acc.w = acc.w * sA + aw * sB;                             \
        m = nm;                                                   \
    }

#define QRED(s)                       \
    s += __shfl_xor(s, 1);            \
    s += __shfl_xor(s, 2);            \
    s += __shfl_xor(s, 4);            \
    s += __shfl_xor(s, 8);

#define DOT4(v, a) ((v).x * (a).x + (v).y * (a).y + (v).z * (a).z + (v).w * (a).w)

// ---------------- prep: attention pools + ad gather (bf16 x) fused with weight transpose ----------------
// Blocks [0, 5120): build_x — wave w = blk*4+waveid; wave split into 4 quarters of 16 lanes,
//   quarter q handles item l+q (float4/lane over K=64).
//   w in [0, 3B): pools; w in [3B, 5B): ad gather (4 features/wave).
// Blocks [5120, 5632): 32x32 LDS-tiled transpose W[K][N] fp32 -> WT[N][K] bf16.
// x row layout (704 bf16): [pool_item(64) | pool_author(64) | pool_music(64) | ad(512)]
__global__ void __launch_bounds__(256) prep_kernel(
    const int* __restrict__ fidx,
    const int* __restrict__ hist_item,
    const int* __restrict__ hist_author,
    const int* __restrict__ hist_music,
    const float* __restrict__ emb,
    const float* __restrict__ W1, const float* __restrict__ W2, const float* __restrict__ W3,
    u16* __restrict__ x,
    u16* __restrict__ w1t, u16* __restrict__ w2t, u16* __restrict__ w3t)
{
    __shared__ float tile[32][33];
    const int blk = blockIdx.x;

    if (blk < 5120) {
        const int w    = blk * 4 + (threadIdx.x >> 6);
        const int lane = threadIdx.x & 63;
        const int t16  = lane & 15;
        const int q    = lane >> 4;

        if (w < 3 * BATCH) {
            const int h = w >> 12;
            const int b = w & (BATCH - 1);
            int L, col, off;
            const int* hrow;
            if (h == 0)      { L = 350; col = 2; off = 0;   hrow = hist_item   + (size_t)b * 350; }
            else if (h == 1) { L = 250; col = 3; off = 64;  hrow = hist_author + (size_t)b * 250; }
            else             { L = 100; col = 6; off = 128; hrow = hist_music  + (size_t)b * 100; }

            const int ad_idx = fidx[b * 8 + col];
            const float4 ad4 = *(const float4*)(emb + (size_t)ad_idx * 64 + 4 * t16);

            // dual softmax states to halve the serial UPD chain
            float m = NEG_INF_F, d = 0.f;
            float4 acc = make_float4(0.f, 0.f, 0.f, 0.f);
            float mB = NEG_INF_F, dB = 0.f;
            float4 aB = make_float4(0.f, 0.f, 0.f, 0.f);

            // Unified predicated loop: ceil(L/16) chunks, OOB items -> PAD
            // (identical semantics to the old main+tail: PAD score = -inf, weight 0).
            // Keeps 4 row-gathers in flight per lane to the very last chunk.
            const int nC = (L + 15) >> 4;
            int n0 = hrow[q], n1 = hrow[4 + q], n2 = hrow[8 + q], n3 = hrow[12 + q];
            int c = 0;
            while (true) {
                const int i0 = n0, i1 = n1, i2 = n2, i3 = n3;
                const float4 v0 = *(const float4*)(emb + (size_t)i0 * 64 + 4 * t16);
                const float4 v1 = *(const float4*)(emb + (size_t)i1 * 64 + 4 * t16);
                const float4 v2 = *(const float4*)(emb + (size_t)i2 * 64 + 4 * t16);
                const float4 v3 = *(const float4*)(emb + (size_t)i3 * 64 + 4 * t16);
                ++c;
                const bool more = (c < nC);
                if (more) {  // prefetch next indices while gathers are in flight
                    const int base = c << 4;
                    const int e0 = base + q,      e1 = base + 4 + q;
                    const int e2 = base + 8 + q,  e3 = base + 12 + q;
                    n0 = (e0 < L) ? hrow[e0] : PAD_IDX;
                    n1 = (e1 < L) ? hrow[e1] : PAD_IDX;
                    n2 = (e2 < L) ? hrow[e2] : PAD_IDX;
                    n3 = (e3 < L) ? hrow[e3] : PAD_IDX;
                }
                float s0 = DOT4(v0, ad4);
                float s1 = DOT4(v1, ad4);
                float s2 = DOT4(v2, ad4);
                float s3 = DOT4(v3, ad4);
                QRED(s0) QRED(s1) QRED(s2) QRED(s3)
                if (i0 == PAD_IDX) s0 = NEG_INF_F;
                if (i1 == PAD_IDX) s1 = NEG_INF_F;
                if (i2 == PAD_IDX) s2 = NEG_INF_F;
                if (i3 == PAD_IDX) s3 = NEG_INF_F;
                UPD(m, d, acc, s0, v0)
                UPD(mB, dB, aB, s1, v1)
                UPD(m, d, acc, s2, v2)
                UPD(mB, dB, aB, s3, v3)
                if (!more) break;
            }

            // merge state B into A (local, no shuffles)
            {
                float nm = fmaxf(m, mB);
                float eA = __expf(m - nm), eB = __expf(mB - nm);
                d = d * eA + dB * eB;
                acc.x = acc.x * eA + aB.x * eB;
                acc.y = acc.y * eA + aB.y * eB;
                acc.z = acc.z * eA + aB.z * eB;
                acc.w = acc.w * eA + aB.w * eB;
                m = nm;
            }
            MERGE(16)
            MERGE(32)

            if (lane < 16) {
                const float inv = 1.f / d;
                uint2 p;
                p.x = (unsigned)f2bf(acc.x * inv) | ((unsigned)f2bf(acc.y * inv) << 16);
                p.y = (unsigned)f2bf(acc.z * inv) | ((unsigned)f2bf(acc.w * inv) << 16);
                *(uint2*)(x + (size_t)b * 704 + off + 4 * t16) = p;
            }
        } else {
            const int tt = w - 3 * BATCH;          // [0, 2B)
            const int b  = tt >> 1;
            const int f  = ((tt & 1) << 2) + q;    // 4 features per wave
            const int idx = fidx[b * 8 + f];
            const float4 v = *(const float4*)(emb + (size_t)idx * 64 + 4 * t16);
            uint2 p;
            p.x = (unsigned)f2bf(v.x) | ((unsigned)f2bf(v.y) << 16);
            p.y = (unsigned)f2bf(v.z) | ((unsigned)f2bf(v.w) << 16);
            *(uint2*)(x + (size_t)b * 704 + 192 + (size_t)f * 64 + 4 * t16) = p;
        }
    } else {
        // ---- weight transpose: 32x32 fp32 tile, coalesced read + coalesced write ----
        int t = blk - 5120;
        const float* W; u16* WT; int K, N, tk, tn;
        if (t < 352)      { W = W1; WT = w1t; K = 704; N = 512; tk = t % 22; tn = t / 22; }
        else if (t < 480) { t -= 352; W = W2; WT = w2t; K = 512; N = 256; tk = t % 16; tn = t / 16; }
        else              { t -= 480; W = W3; WT = w3t; K = 256; N = 128; tk = t % 8;  tn = t / 8;  }
        const int k0 = tk * 32, n0 = tn * 32;
        const int tx = threadIdx.x & 31, ty = threadIdx.x >> 5;   // ty 0..7
#pragma unroll
        for (int j = 0; j < 4; ++j)
            tile[ty + 8 * j][tx] = W[(size_t)(k0 + ty + 8 * j) * N + n0 + tx];
        __syncthreads();
#pragma unroll
        for (int j = 0; j < 4; ++j)
            WT[(size_t)(n0 + ty + 8 * j) * K + k0 + tx] = f2bf(tile[tx][ty + 8 * j]);
    }
}

// ---------------- bf16 MFMA GEMM: C[M,N] = relu(A[M,K] @ BT[N,K]^T + bias), bf16 out ----------------
// BM=64, 256 threads = 4 waves, BK=32. LDS rows padded to 40 bf16 (80 B).
// T3-min/T14 pipeline: register-prefetch next K-tile, LDS double-buffer,
// ONE barrier per iteration (reads hit buf[cur], writes hit buf[cur^1] — disjoint;
// a wave's ds_reads are drained before its own barrier, so the single barrier is safe).
template <int BN>
__global__ void __launch_bounds__(256) gemm_mfma(
    const u16* __restrict__ A, const u16* __restrict__ BT,
    const float* __restrict__ bias, u16* __restrict__ C,
    int M, int N, int K)
{
    constexpr int NB = BN / 16;
    constexpr int RB = BN / 64;
    __shared__ u16 As[2][64][40];
    __shared__ u16 Bs[2][BN][40];

    const int tid  = threadIdx.x;
    const int wave = tid >> 6, lane = tid & 63;
    const int quad = lane >> 4, l16 = lane & 15;
    const int bm = blockIdx.y * 64, bn = blockIdx.x * BN;

    const int srow = tid >> 2;          // 0..63
    const int sk   = (tid & 3) * 8;     // 0,8,16,24

    f32x4 acc[NB];
#pragma unroll
    for (int i = 0; i < NB; ++i) acc[i] = (f32x4){0.f, 0.f, 0.f, 0.f};

    const u16* aptr = A  + (size_t)(bm + srow) * K + sk;
    const u16* bptr = BT + (size_t)(bn + srow) * K + sk;

    // prologue: tile 0 -> regs -> LDS buf 0
    float4 ra = *(const float4*)aptr;
    float4 rb[RB];
#pragma unroll
    for (int r = 0; r < RB; ++r)
        rb[r] = *(const float4*)(bptr + (size_t)(r * 64) * K);

    *(float4*)&As[0][srow][sk] = ra;
#pragma unroll
    for (int r = 0; r < RB; ++r)
        *(float4*)&Bs[0][r * 64 + srow][sk] = rb[r];
    __syncthreads();

    int cur = 0;
    for (int k0 = 0; k0 < K; k0 += 32) {
        const bool more = (k0 + 32 < K);
        if (more) {   // issue next-tile global loads; latency hides under ds_read+MFMA
            ra = *(const float4*)(aptr + k0 + 32);
#pragma unroll
            for (int r = 0; r < RB; ++r)
                rb[r] = *(const float4*)(bptr + (size_t)(r * 64) * K + k0 + 32);
        }

        const bf16x8 af = *(const bf16x8*)&As[cur][wave * 16 + l16][quad * 8];
#pragma unroll
        for (int ni = 0; ni < NB; ++ni) {
            const bf16x8 bf = *(const bf16x8*)&Bs[cur][ni * 16 + l16][quad * 8];
            acc[ni] = __builtin_amdgcn_mfma_f32_16x16x32_bf16(af, bf, acc[ni], 0, 0, 0);
        }

        if (more) {
            *(float4*)&As[cur ^ 1][srow][sk] = ra;
#pragma unroll
            for (int r = 0; r < RB; ++r)
                *(float4*)&Bs[cur ^ 1][r * 64 + srow][sk] = rb[r];
            __syncthreads();
            cur ^= 1;
        }
    }

#pragma unroll
    for (int ni = 0; ni < NB; ++ni) {
        const int col = bn + ni * 16 + l16;
        const float bv = bias[col];
#pragma unroll
        for (int r = 0; r < 4; ++r) {
            const int row = bm + wave * 16 + quad * 4 + r;
            float v = fmaxf(acc[ni][r] + bv, 0.f);
            C[(size_t)row * N + col] = f2bf(v);
        }
    }
}

// ---------------- fused layer 3 + output: out = relu(h2 @ W3T^T + b3) @ Wo + bo ----------------
// M=4096, N=128, K=256. One block covers 64 rows x all 128 cols; grid = 64 blocks.
// Same single-barrier double-buffered pipeline as gemm_mfma.
__global__ void __launch_bounds__(256) gemm3_out(
    const u16* __restrict__ A, const u16* __restrict__ BT,
    const float* __restrict__ bias,
    const float* __restrict__ Wo, const float* __restrict__ bo,
    float* __restrict__ out)
{
    constexpr int K = 256, NB = 8;
    __shared__ u16 As[2][64][40];
    __shared__ u16 Bs[2][128][40];

    const int tid  = threadIdx.x;
    const int wave = tid >> 6, lane = tid & 63;
    const int quad = lane >> 4, l16 = lane & 15;
    const int bm = blockIdx.x * 64;

    const int srow = tid >> 2;
    const int sk   = (tid & 3) * 8;

    f32x4 acc[NB];
#pragma unroll
    for (int i = 0; i < NB; ++i) acc[i] = (f32x4){0.f, 0.f, 0.f, 0.f};

    const u16* aptr = A  + (size_t)(bm + srow) * K + sk;
    const u16* bptr = BT + (size_t)srow * K + sk;

    float4 ra = *(const float4*)aptr;
    float4 rb[2];
#pragma unroll
    for (int r = 0; r < 2; ++r)
        rb[r] = *(const float4*)(bptr + (size_t)(r * 64) * K);

    *(float4*)&As[0][srow][sk] = ra;
#pragma unroll
    for (int r = 0; r < 2; ++r)
        *(float4*)&Bs[0][r * 64 + srow][sk] = rb[r];
    __syncthreads();

    int cur = 0;
    for (int k0 = 0; k0 < K; k0 += 32) {
        const bool more = (k0 + 32 < K);
        if (more) {
            ra = *(const float4*)(aptr + k0 + 32);
#pragma unroll
            for (int r = 0; r < 2; ++r)
                rb[r] = *(const float4*)(bptr + (size_t)(r * 64) * K + k0 + 32);
        }

        const bf16x8 af = *(const bf16x8*)&As[cur][wave * 16 + l16][quad * 8];
#pragma unroll
        for (int ni = 0; ni < NB; ++ni) {
            const bf16x8 bf = *(const bf16x8*)&Bs[cur][ni * 16 + l16][quad * 8];
            acc[ni] = __builtin_amdgcn_mfma_f32_16x16x32_bf16(af, bf, acc[ni], 0, 0, 0);
        }

        if (more) {
            *(float4*)&As[cur ^ 1][srow][sk] = ra;
#pragma unroll
            for (int r = 0; r < 2; ++r)
                *(float4*)&Bs[cur ^ 1][r * 64 + srow][sk] = rb[r];
            __syncthreads();
            cur ^= 1;
        }
    }

    // epilogue: relu(+bias), dot with Wo across the 128 cols, reduce over 16 lanes
    float part[4] = {0.f, 0.f, 0.f, 0.f};
#pragma unroll
    for (int ni = 0; ni < NB; ++ni) {
        const int col = ni * 16 + l16;
        const float bv = bias[col];
        const float wv = Wo[col];
#pragma unroll
        for (int r = 0; r < 4; ++r)
            part[r] = fmaf(fmaxf(acc[ni][r] + bv, 0.f), wv, part[r]);
    }
#pragma unroll
    for (int r = 0; r < 4; ++r) {
        part[r] += __shfl_xor(part[r], 1);
        part[r] += __shfl_xor(part[r], 2);
        part[r] += __shfl_xor(part[r], 4);
        part[r] += __shfl_xor(part[r], 8);
    }
    if (l16 == 0) {
        const float b0 = bo[0];
#pragma unroll
        for (int r = 0; r < 4; ++r)
            out[bm + wave * 16 + quad * 4 + r] = part[r] + b0;
    }
}

extern "C" void kernel_launch(void* const* d_in, const int* in_sizes, int n_in,
                              void* d_out, int out_size, void* d_ws, size_t ws_size,
                              hipStream_t stream) {
    const int*   fidx  = (const int*)d_in[0];
    const int*   hitem = (const int*)d_in[1];
    const int*   hauth = (const int*)d_in[2];
    const int*   hmus  = (const int*)d_in[3];
    const float* emb   = (const float*)d_in[4];
    const float* W1 = (const float*)d_in[5];
    const float* b1 = (const float*)d_in[6];
    const float* W2 = (const float*)d_in[7];
    const float* b2 = (const float*)d_in[8];
    const float* W3 = (const float*)d_in[9];
    const float* b3 = (const float*)d_in[10];
    const float* Wo = (const float*)d_in[11];
    const float* bo = (const float*)d_in[12];
    float* out = (float*)d_out;

    // workspace carve (bf16 elements, all 16B-aligned)
    u16* x   = (u16*)d_ws;                     // 4096*704
    u16* h1  = x   + (size_t)BATCH * 704;      // 4096*512
    u16* h2  = h1  + (size_t)BATCH * 512;      // 4096*256
    u16* w1t = h2  + (size_t)BATCH * 256;      // 512*704
    u16* w2t = w1t + (size_t)704 * 512;        // 256*512
    u16* w3t = w2t + (size_t)512 * 256;        // 128*256

    // 5120 build_x blocks + 512 transpose blocks
    prep_kernel<<<5632, 256, 0, stream>>>(fidx, hitem, hauth, hmus, emb,
                                          W1, W2, W3, x, w1t, w2t, w3t);

    gemm_mfma<64><<<dim3(512 / 64, BATCH / 64), 256, 0, stream>>>(
        x, w1t, b1, h1, BATCH, 512, 704);
    gemm_mfma<64><<<dim3(256 / 64, BATCH / 64), 256, 0, stream>>>(
        h1, w2t, b2, h2, BATCH, 256, 512);
    gemm3_out<<<BATCH / 64, 256, 0, stream>>>(h2, w3t, b3, Wo, bo, out);
}